// Round 6
// baseline (351.463 us; speedup 1.0000x reference)
//
#include <hip/hip_runtime.h>

constexpr int N    = 100000;
constexpr int E    = 1000000;
constexpr int FIN  = 64;
constexpr int HID  = 128;
constexpr int NCLS = 32;
constexpr int G    = 1024;
constexpr float EPS = 1e-5f;

constexpr int SCAN_B = (N + 1023) / 1024;  // 98 blocks
constexpr int NTILE  = (N + 127) / 128;    // 782 row tiles

// histogram of dst -> counts (in-degree, excludes self loop)
__global__ void k_hist(const int4* __restrict__ dst4, int* __restrict__ counts) {
  int t = blockIdx.x * blockDim.x + threadIdx.x;
  if (t < E / 4) {
    int4 d = dst4[t];
    atomicAdd(&counts[d.x], 1);
    atomicAdd(&counts[d.y], 1);
    atomicAdd(&counts[d.z], 1);
    atomicAdd(&counts[d.w], 1);
  }
}

// phase 1: per-block sums
__global__ __launch_bounds__(1024) void k_scan1(const int* __restrict__ counts,
                                                int* __restrict__ blocksum) {
  __shared__ int red[1024];
  int tid = threadIdx.x;
  int i = blockIdx.x * 1024 + tid;
  red[tid] = (i < N) ? counts[i] : 0;
  __syncthreads();
  for (int off = 512; off > 0; off >>= 1) {
    if (tid < off) red[tid] += red[tid + off];
    __syncthreads();
  }
  if (tid == 0) blocksum[blockIdx.x] = red[0];
}

// phase 2: exclusive scan of SCAN_B block sums (single small block)
__global__ __launch_bounds__(128) void k_scan2(int* __restrict__ blocksum) {
  __shared__ int part[128];
  int tid = threadIdx.x;
  int v = (tid < SCAN_B) ? blocksum[tid] : 0;
  part[tid] = v;
  __syncthreads();
  for (int off = 1; off < 128; off <<= 1) {
    int t = (tid >= off) ? part[tid - off] : 0;
    __syncthreads();
    part[tid] += t;
    __syncthreads();
  }
  if (tid < SCAN_B) blocksum[tid] = part[tid] - v;  // exclusive
}

// phase 3: per-block scan + base -> offsets, cursor; also dinv = rsqrt(count+1)
__global__ __launch_bounds__(1024) void k_scan3(const int* __restrict__ counts,
                                                const int* __restrict__ blocksum,
                                                int* __restrict__ offsets,
                                                int* __restrict__ cursor,
                                                float* __restrict__ dinv) {
  __shared__ int part[1024];
  int tid = threadIdx.x;
  int i = blockIdx.x * 1024 + tid;
  int v = (i < N) ? counts[i] : 0;
  part[tid] = v;
  __syncthreads();
  for (int off = 1; off < 1024; off <<= 1) {
    int t = (tid >= off) ? part[tid - off] : 0;
    __syncthreads();
    part[tid] += t;
    __syncthreads();
  }
  int base = blocksum[blockIdx.x];
  int excl = base + part[tid] - v;
  if (i < N) {
    offsets[i] = excl;
    cursor[i]  = excl;
    dinv[i]    = rsqrtf((float)v + 1.0f);
    if (i == N - 1) offsets[N] = excl + v;  // == E
  }
}

// scatter src ids into CSR order; nontemporal stores avoid L2 line write-amp
__global__ void k_fill(const int4* __restrict__ src4, const int4* __restrict__ dst4,
                       int* __restrict__ cursor, int* __restrict__ srclist) {
  int t = blockIdx.x * blockDim.x + threadIdx.x;
  if (t < E / 4) {
    int4 s = src4[t];
    int4 d = dst4[t];
    int p0 = atomicAdd(&cursor[d.x], 1);
    int p1 = atomicAdd(&cursor[d.y], 1);
    int p2 = atomicAdd(&cursor[d.z], 1);
    int p3 = atomicAdd(&cursor[d.w], 1);
    __builtin_nontemporal_store(s.x, &srclist[p0]);
    __builtin_nontemporal_store(s.y, &srclist[p1]);
    __builtin_nontemporal_store(s.z, &srclist[p2]);
    __builtin_nontemporal_store(s.w, &srclist[p3]);
  }
}

// one 16-lane group per node: agg[d] = dinv[d]*( x[d]*dinv[d] + sum_s x[s]*dinv[s] )
__global__ __launch_bounds__(256) void k_gather(const int* __restrict__ offsets,
                                                const int* __restrict__ srclist,
                                                const float* __restrict__ dinv,
                                                const float4* __restrict__ x4,
                                                float4* __restrict__ agg4) {
  int node = blockIdx.x * 16 + (threadIdx.x >> 4);
  int lane = threadIdx.x & 15;
  if (node >= N) return;
  int start = offsets[node], end = offsets[node + 1];
  float cd = dinv[node];
  float4 acc = x4[node * 16 + lane];
  acc.x *= cd; acc.y *= cd; acc.z *= cd; acc.w *= cd;
  for (int i = start; i < end; ++i) {
    int s = srclist[i];
    float cs = dinv[s];
    float4 v = x4[s * 16 + lane];
    acc.x += v.x * cs; acc.y += v.y * cs; acc.z += v.z * cs; acc.w += v.w * cs;
  }
  acc.x *= cd; acc.y *= cd; acc.z *= cd; acc.w *= cd;
  agg4[node * 16 + lane] = acc;
}

// h[N,128] = agg[N,64] @ W[64,128] + b, fused BN1 stats via per-block atomics.
// 256 thr: rt=tid>>4 (16 row-threads x 8 rows), ct=tid&15 (16 col-threads x 8 cols).
__global__ __launch_bounds__(256) void k_gemm2(const float* __restrict__ agg,
                                               const float* __restrict__ W,
                                               const float* __restrict__ b,
                                               float* __restrict__ h,
                                               float* __restrict__ sums) {
  __shared__ float Wl[64 * 128];    // [k][col]
  __shared__ float rowT[64 * 128];  // [k][row]  (transposed agg tile)
  int tid  = threadIdx.x;
  int row0 = blockIdx.x * 128;
  // stage W (straight copy, float4)
  {
    const float4* Wg4 = (const float4*)W;
    float4* Wl4 = (float4*)Wl;
    for (int i = tid; i < 2048; i += 256) Wl4[i] = Wg4[i];
  }
  // stage agg tile transposed: thread handles row r=tid&127, k-half kh=tid>>7
  {
    int r = tid & 127, kh = tid >> 7;
    int grow = row0 + r;
#pragma unroll
    for (int i = 0; i < 8; ++i) {
      int k0 = kh * 32 + i * 4;
      float4 v;
      if (grow < N) v = *(const float4*)&agg[(long long)grow * 64 + k0];
      else          v = make_float4(0.f, 0.f, 0.f, 0.f);
      rowT[(k0 + 0) * 128 + r] = v.x;
      rowT[(k0 + 1) * 128 + r] = v.y;
      rowT[(k0 + 2) * 128 + r] = v.z;
      rowT[(k0 + 3) * 128 + r] = v.w;
    }
  }
  __syncthreads();

  int rt = tid >> 4, ct = tid & 15;
  float acc[8][8];
#pragma unroll
  for (int m = 0; m < 8; ++m)
#pragma unroll
    for (int j = 0; j < 8; ++j) acc[m][j] = 0.f;

#pragma unroll 4
  for (int k = 0; k < 64; ++k) {
    float4 w0 = *(const float4*)&Wl[k * 128 + ct * 8];
    float4 w1 = *(const float4*)&Wl[k * 128 + ct * 8 + 4];
    float4 r0 = *(const float4*)&rowT[k * 128 + rt * 8];
    float4 r1 = *(const float4*)&rowT[k * 128 + rt * 8 + 4];
    float wv[8] = {w0.x, w0.y, w0.z, w0.w, w1.x, w1.y, w1.z, w1.w};
    float rv[8] = {r0.x, r0.y, r0.z, r0.w, r1.x, r1.y, r1.z, r1.w};
#pragma unroll
    for (int m = 0; m < 8; ++m)
#pragma unroll
      for (int j = 0; j < 8; ++j) acc[m][j] += rv[m] * wv[j];
  }

  int cbase = ct * 8;
  float4 b0 = *(const float4*)&b[cbase];
  float4 b1 = *(const float4*)&b[cbase + 4];
  float bias[8] = {b0.x, b0.y, b0.z, b0.w, b1.x, b1.y, b1.z, b1.w};
  float s[8], s2[8];
#pragma unroll
  for (int j = 0; j < 8; ++j) { s[j] = 0.f; s2[j] = 0.f; }
#pragma unroll
  for (int m = 0; m < 8; ++m) {
    int grow = row0 + rt * 8 + m;
    if (grow < N) {
      float hv[8];
#pragma unroll
      for (int j = 0; j < 8; ++j) {
        hv[j] = acc[m][j] + bias[j];
        s[j] += hv[j];
        s2[j] += hv[j] * hv[j];
      }
      float* hp = &h[(long long)grow * 128 + cbase];
      *(float4*)hp       = make_float4(hv[0], hv[1], hv[2], hv[3]);
      *(float4*)(hp + 4) = make_float4(hv[4], hv[5], hv[6], hv[7]);
    }
  }
  // reduce stats over the 16 rt-threads in LDS, then one atomic per column pair
  __syncthreads();
  float* red = Wl;  // 16 * 256 floats scratch
#pragma unroll
  for (int j = 0; j < 8; ++j) {
    red[rt * 256 + cbase + j]       = s[j];
    red[rt * 256 + 128 + cbase + j] = s2[j];
  }
  __syncthreads();
  float tot = 0.f;
#pragma unroll 4
  for (int r = 0; r < 16; ++r) tot += red[r * 256 + tid];
  atomicAdd(&sums[tid], tot);  // [0:128)=sum, [128:256)=sumsq
}

// sums -> scale/shift
__global__ __launch_bounds__(128) void k_bn1_final(const float* __restrict__ sums,
                                                   const float* __restrict__ w,
                                                   const float* __restrict__ bb,
                                                   float* __restrict__ ss) {
  int tid = threadIdx.x;
  float mu  = sums[tid] * (1.0f / N);
  float var = sums[tid + 128] * (1.0f / N) - mu * mu;
  float rs  = rsqrtf(var + EPS);
  float sc  = rs * w[tid];
  ss[tid]       = sc;
  ss[tid + 128] = bb[tid] - mu * sc;
}

// one block per graph: BN1-normalize + ReLU + mean pool (batch is sorted)
__global__ __launch_bounds__(256) void k_pool(const float* __restrict__ h,
                                              const float* __restrict__ ss,
                                              const int* __restrict__ batch,
                                              float* __restrict__ pooled) {
  int g = blockIdx.x;
  int lo = 0, hi = N;
  while (lo < hi) { int m = (lo + hi) >> 1; if (batch[m] < g) lo = m + 1; else hi = m; }
  int lo2 = lo, hi2 = N;
  while (lo2 < hi2) { int m = (lo2 + hi2) >> 1; if (batch[m] < g + 1) lo2 = m + 1; else hi2 = m; }
  int start = lo, end = lo2;
  int tid = threadIdx.x;
  int col = tid & 127, rp = tid >> 7;
  float sc = ss[col], sh = ss[col + 128];
  float s = 0.f;
  for (int r = start + rp; r < end; r += 2) {
    float v = h[(long long)r * 128 + col] * sc + sh;
    s += fmaxf(v, 0.f);
  }
  __shared__ float red[256];
  red[tid] = s;
  __syncthreads();
  if (tid < 128) {
    float cnt = fmaxf((float)(end - start), 1.0f);
    pooled[g * 128 + col] = (red[tid] + red[tid + 128]) / cnt;
  }
}

__global__ __launch_bounds__(256) void k_head(const float* __restrict__ pooled,
                                              const float* __restrict__ W,
                                              const float* __restrict__ b,
                                              float* __restrict__ outpre) {
  int idx = blockIdx.x * blockDim.x + threadIdx.x;
  if (idx >= G * NCLS) return;
  int g = idx >> 5, c = idx & 31;
  float acc = b[c];
  const float* pr = pooled + g * 128;
#pragma unroll
  for (int k = 0; k < 128; ++k) acc += pr[k] * W[k * 32 + c];
  outpre[idx] = acc;
}

__global__ __launch_bounds__(1024) void k_bn2(const float* __restrict__ outpre,
                                              const float* __restrict__ w,
                                              const float* __restrict__ b,
                                              float* __restrict__ out) {
  __shared__ float red[1024];
  __shared__ float mus[32], rss[32];
  int tid = threadIdx.x;
  int col = tid & 31, grp = tid >> 5;
  float s = 0.f;
  for (int r = grp; r < G; r += 32) s += outpre[r * 32 + col];
  red[tid] = s;
  __syncthreads();
  for (int off = 512; off >= 32; off >>= 1) {
    if (tid < off) red[tid] += red[tid + off];
    __syncthreads();
  }
  if (tid < 32) mus[col] = red[col] * (1.0f / G);
  __syncthreads();
  float mu = mus[col];
  float s2 = 0.f;
  for (int r = grp; r < G; r += 32) { float d = outpre[r * 32 + col] - mu; s2 += d * d; }
  __syncthreads();
  red[tid] = s2;
  __syncthreads();
  for (int off = 512; off >= 32; off >>= 1) {
    if (tid < off) red[tid] += red[tid + off];
    __syncthreads();
  }
  if (tid < 32) rss[col] = rsqrtf(red[col] * (1.0f / G) + EPS);
  __syncthreads();
  float rs = rss[col], wc = w[col], bc = b[col];
  for (int r = grp; r < G; r += 32)
    out[r * 32 + col] = (outpre[r * 32 + col] - mu) * rs * wc + bc;
}

extern "C" void kernel_launch(void* const* d_in, const int* in_sizes, int n_in,
                              void* d_out, int out_size, void* d_ws, size_t ws_size,
                              hipStream_t stream) {
  const float* x   = (const float*)d_in[0];
  const int* ei    = (const int*)d_in[1];
  const int* batch = (const int*)d_in[2];
  const float* Wg  = (const float*)d_in[3];
  const float* bg  = (const float*)d_in[4];
  const float* w1  = (const float*)d_in[5];
  const float* b1  = (const float*)d_in[6];
  const float* Wo  = (const float*)d_in[7];
  const float* bo  = (const float*)d_in[8];
  const float* w2  = (const float*)d_in[9];
  const float* b2  = (const float*)d_in[10];

  float* ws     = (float*)d_ws;
  float* dinv   = ws;                       // 100352
  float* agg    = ws + 100352;              // N*64
  float* h      = agg + (long long)N * 64;  // N*128
  float* ss     = h + (long long)N * 128;   // 256 (BN1 scale/shift)
  float* sums   = ss + 256;                 // 256 (BN1 atomic accumulators)
  float* pooled = sums + 256;               // G*128
  float* outpre = pooled + G * 128;         // G*32
  int* counts   = (int*)(outpre + G * 32);  // 100352
  int* offsets  = counts + 100352;          // N+1 (padded)
  int* cursor   = offsets + 100416;         // 100352
  int* srclist  = cursor + 100352;          // E
  int* blocksum = srclist + E;              // SCAN_B (padded 128)

  const int* src = ei;
  const int* dst = ei + E;

  hipMemsetAsync(counts, 0, 100352 * sizeof(int), stream);
  hipMemsetAsync(sums, 0, 256 * sizeof(float), stream);
  k_hist<<<(E / 4 + 255) / 256, 256, 0, stream>>>((const int4*)dst, counts);
  k_scan1<<<SCAN_B, 1024, 0, stream>>>(counts, blocksum);
  k_scan2<<<1, 128, 0, stream>>>(blocksum);
  k_scan3<<<SCAN_B, 1024, 0, stream>>>(counts, blocksum, offsets, cursor, dinv);
  k_fill<<<(E / 4 + 255) / 256, 256, 0, stream>>>((const int4*)src, (const int4*)dst,
                                                  cursor, srclist);
  k_gather<<<(N + 15) / 16, 256, 0, stream>>>(offsets, srclist, dinv,
                                              (const float4*)x, (float4*)agg);
  k_gemm2<<<NTILE, 256, 0, stream>>>(agg, Wg, bg, h, sums);
  k_bn1_final<<<1, 128, 0, stream>>>(sums, w1, b1, ss);
  k_pool<<<G, 256, 0, stream>>>(h, ss, batch, pooled);
  k_head<<<(G * NCLS + 255) / 256, 256, 0, stream>>>(pooled, Wo, bo, outpre);
  k_bn2<<<1, 1024, 0, stream>>>(outpre, w2, b2, (float*)d_out);
}

// Round 7
// 269.915 us; speedup vs baseline: 1.3021x; 1.3021x over previous
//
#include <hip/hip_runtime.h>

constexpr int N    = 100000;
constexpr int E    = 1000000;
constexpr int FIN  = 64;
constexpr int HID  = 128;
constexpr int NCLS = 32;
constexpr int G    = 1024;
constexpr float EPS = 1e-5f;

constexpr int NTILE = (N + 127) / 128;  // 782 row tiles for GEMM

// ---- binned CSR build ----
constexpr int NBUCK = 49;      // dst >> 11, nodes 0..99999 -> buckets 0..48
constexpr int NPB   = 2048;    // nodes per bucket
constexpr int EPB   = 2048;    // edges per k_bin block
constexpr int CAP   = 24576;   // bucket capacity (mean 20480, sigma ~143)
constexpr int BIN_GRID = (E + EPB - 1) / EPB;  // 489

// multi-split edges into buckets by dst>>11; coalesced (src,dst) pair appends
__global__ __launch_bounds__(256) void k_bin(const int* __restrict__ src,
                                             const int* __restrict__ dst,
                                             int* __restrict__ bucketCursor,
                                             uint2* __restrict__ bucketBuf) {
  __shared__ int bcnt[NBUCK];
  __shared__ int bscan[NBUCK];
  __shared__ int bdelta[NBUCK];
  __shared__ int lcur[NBUCK];
  __shared__ uint2 staged[EPB];  // 16 KB
  int tid = threadIdx.x;
  int e0 = blockIdx.x * EPB;
  int cnt = E - e0 < EPB ? E - e0 : EPB;
  for (int i = tid; i < NBUCK; i += 256) bcnt[i] = 0;
  __syncthreads();
  for (int i = tid; i < cnt; i += 256) {
    int d = dst[e0 + i];
    atomicAdd(&bcnt[d >> 11], 1);
  }
  __syncthreads();
  if (tid == 0) {
    int run = 0;
    for (int b = 0; b < NBUCK; ++b) { bscan[b] = run; run += bcnt[b]; }
  }
  __syncthreads();
  if (tid < NBUCK) {
    int base = bcnt[tid] ? atomicAdd(&bucketCursor[tid], bcnt[tid]) : 0;
    bdelta[tid] = base - bscan[tid];
    lcur[tid]   = bscan[tid];
  }
  __syncthreads();
  for (int i = tid; i < cnt; i += 256) {
    int s = src[e0 + i], d = dst[e0 + i];
    int pos = atomicAdd(&lcur[d >> 11], 1);
    staged[pos] = make_uint2((unsigned)s, (unsigned)d);
  }
  __syncthreads();
  for (int i = tid; i < cnt; i += 256) {
    uint2 p = staged[i];
    int b = (int)(p.y >> 11);
    bucketBuf[(long long)b * CAP + bdelta[b] + i] = p;
  }
}

// one block per bucket: LDS count -> offsets+dinv, then LDS-cursor scatter to srclist
__global__ __launch_bounds__(1024) void k_build(const int* __restrict__ bucketLen,
                                                const uint2* __restrict__ bucketBuf,
                                                int* __restrict__ offsets,
                                                float* __restrict__ dinv,
                                                int* __restrict__ srclist) {
  __shared__ int cnt[NPB];    // counts, then cursors
  __shared__ int part[1024];
  __shared__ int bbase;
  int b = blockIdx.x, tid = threadIdx.x;
  int n0 = b << 11;
  int nn = (N - n0 < NPB) ? (N - n0) : NPB;
  int len = bucketLen[b];
  cnt[tid] = 0; cnt[tid + 1024] = 0;
  __syncthreads();
  const uint2* buf = bucketBuf + (long long)b * CAP;
  for (int i = tid; i < len; i += 1024)
    atomicAdd(&cnt[(int)buf[i].y - n0], 1);
  if (tid == 0) {  // exclusive scan of bucket lengths up to b (49 adds, trivial)
    int s = 0;
    for (int j = 0; j < b; ++j) s += bucketLen[j];
    bbase = s;
  }
  __syncthreads();
  int c0 = cnt[2 * tid], c1 = cnt[2 * tid + 1];
  int psum = c0 + c1;
  part[tid] = psum;
  __syncthreads();
  for (int off = 1; off < 1024; off <<= 1) {
    int t = (tid >= off) ? part[tid - off] : 0;
    __syncthreads();
    part[tid] += t;
    __syncthreads();
  }
  int excl = part[tid] - psum;
  int base = bbase;
  int o0 = base + excl, o1 = base + excl + c0;
  __syncthreads();  // done reading cnt as counts
  cnt[2 * tid] = o0; cnt[2 * tid + 1] = o1;
  if (2 * tid < nn) {
    offsets[n0 + 2 * tid] = o0;
    dinv[n0 + 2 * tid] = rsqrtf((float)c0 + 1.0f);
  }
  if (2 * tid + 1 < nn) {
    offsets[n0 + 2 * tid + 1] = o1;
    dinv[n0 + 2 * tid + 1] = rsqrtf((float)c1 + 1.0f);
  }
  if (b == NBUCK - 1 && tid == 1023) offsets[N] = base + part[1023];  // == E
  __syncthreads();
  for (int i = tid; i < len; i += 1024) {
    uint2 p = buf[i];
    int pos = atomicAdd(&cnt[(int)p.y - n0], 1);
    srclist[pos] = (int)p.x;
  }
}

// one 16-lane group per node: agg[d] = dinv[d]*( x[d]*dinv[d] + sum_s x[s]*dinv[s] )
__global__ __launch_bounds__(256) void k_gather(const int* __restrict__ offsets,
                                                const int* __restrict__ srclist,
                                                const float* __restrict__ dinv,
                                                const float4* __restrict__ x4,
                                                float4* __restrict__ agg4) {
  int node = blockIdx.x * 16 + (threadIdx.x >> 4);
  int lane = threadIdx.x & 15;
  if (node >= N) return;
  int start = offsets[node], end = offsets[node + 1];
  float cd = dinv[node];
  float4 acc = x4[node * 16 + lane];
  acc.x *= cd; acc.y *= cd; acc.z *= cd; acc.w *= cd;
  for (int i = start; i < end; ++i) {
    int s = srclist[i];
    float cs = dinv[s];
    float4 v = x4[s * 16 + lane];
    acc.x += v.x * cs; acc.y += v.y * cs; acc.z += v.z * cs; acc.w += v.w * cs;
  }
  acc.x *= cd; acc.y *= cd; acc.z *= cd; acc.w *= cd;
  agg4[node * 16 + lane] = acc;
}

// h[N,128] = agg[N,64] @ W[64,128] + b, fused BN1 stats via per-block atomics.
__global__ __launch_bounds__(256) void k_gemm2(const float* __restrict__ agg,
                                               const float* __restrict__ W,
                                               const float* __restrict__ b,
                                               float* __restrict__ h,
                                               float* __restrict__ sums) {
  __shared__ float Wl[64 * 128];
  __shared__ float rowT[64 * 128];
  int tid  = threadIdx.x;
  int row0 = blockIdx.x * 128;
  {
    const float4* Wg4 = (const float4*)W;
    float4* Wl4 = (float4*)Wl;
    for (int i = tid; i < 2048; i += 256) Wl4[i] = Wg4[i];
  }
  {
    int r = tid & 127, kh = tid >> 7;
    int grow = row0 + r;
#pragma unroll
    for (int i = 0; i < 8; ++i) {
      int k0 = kh * 32 + i * 4;
      float4 v;
      if (grow < N) v = *(const float4*)&agg[(long long)grow * 64 + k0];
      else          v = make_float4(0.f, 0.f, 0.f, 0.f);
      rowT[(k0 + 0) * 128 + r] = v.x;
      rowT[(k0 + 1) * 128 + r] = v.y;
      rowT[(k0 + 2) * 128 + r] = v.z;
      rowT[(k0 + 3) * 128 + r] = v.w;
    }
  }
  __syncthreads();

  int rt = tid >> 4, ct = tid & 15;
  float acc[8][8];
#pragma unroll
  for (int m = 0; m < 8; ++m)
#pragma unroll
    for (int j = 0; j < 8; ++j) acc[m][j] = 0.f;

#pragma unroll 4
  for (int k = 0; k < 64; ++k) {
    float4 w0 = *(const float4*)&Wl[k * 128 + ct * 8];
    float4 w1 = *(const float4*)&Wl[k * 128 + ct * 8 + 4];
    float4 r0 = *(const float4*)&rowT[k * 128 + rt * 8];
    float4 r1 = *(const float4*)&rowT[k * 128 + rt * 8 + 4];
    float wv[8] = {w0.x, w0.y, w0.z, w0.w, w1.x, w1.y, w1.z, w1.w};
    float rv[8] = {r0.x, r0.y, r0.z, r0.w, r1.x, r1.y, r1.z, r1.w};
#pragma unroll
    for (int m = 0; m < 8; ++m)
#pragma unroll
      for (int j = 0; j < 8; ++j) acc[m][j] += rv[m] * wv[j];
  }

  int cbase = ct * 8;
  float4 b0 = *(const float4*)&b[cbase];
  float4 b1 = *(const float4*)&b[cbase + 4];
  float bias[8] = {b0.x, b0.y, b0.z, b0.w, b1.x, b1.y, b1.z, b1.w};
  float s[8], s2[8];
#pragma unroll
  for (int j = 0; j < 8; ++j) { s[j] = 0.f; s2[j] = 0.f; }
#pragma unroll
  for (int m = 0; m < 8; ++m) {
    int grow = row0 + rt * 8 + m;
    if (grow < N) {
      float hv[8];
#pragma unroll
      for (int j = 0; j < 8; ++j) {
        hv[j] = acc[m][j] + bias[j];
        s[j] += hv[j];
        s2[j] += hv[j] * hv[j];
      }
      float* hp = &h[(long long)grow * 128 + cbase];
      *(float4*)hp       = make_float4(hv[0], hv[1], hv[2], hv[3]);
      *(float4*)(hp + 4) = make_float4(hv[4], hv[5], hv[6], hv[7]);
    }
  }
  __syncthreads();
  float* red = Wl;
#pragma unroll
  for (int j = 0; j < 8; ++j) {
    red[rt * 256 + cbase + j]       = s[j];
    red[rt * 256 + 128 + cbase + j] = s2[j];
  }
  __syncthreads();
  float tot = 0.f;
#pragma unroll 4
  for (int r = 0; r < 16; ++r) tot += red[r * 256 + tid];
  atomicAdd(&sums[tid], tot);
}

__global__ __launch_bounds__(128) void k_bn1_final(const float* __restrict__ sums,
                                                   const float* __restrict__ w,
                                                   const float* __restrict__ bb,
                                                   float* __restrict__ ss) {
  int tid = threadIdx.x;
  float mu  = sums[tid] * (1.0f / N);
  float var = sums[tid + 128] * (1.0f / N) - mu * mu;
  float rs  = rsqrtf(var + EPS);
  float sc  = rs * w[tid];
  ss[tid]       = sc;
  ss[tid + 128] = bb[tid] - mu * sc;
}

__global__ __launch_bounds__(256) void k_pool(const float* __restrict__ h,
                                              const float* __restrict__ ss,
                                              const int* __restrict__ batch,
                                              float* __restrict__ pooled) {
  int g = blockIdx.x;
  int lo = 0, hi = N;
  while (lo < hi) { int m = (lo + hi) >> 1; if (batch[m] < g) lo = m + 1; else hi = m; }
  int lo2 = lo, hi2 = N;
  while (lo2 < hi2) { int m = (lo2 + hi2) >> 1; if (batch[m] < g + 1) lo2 = m + 1; else hi2 = m; }
  int start = lo, end = lo2;
  int tid = threadIdx.x;
  int col = tid & 127, rp = tid >> 7;
  float sc = ss[col], sh = ss[col + 128];
  float s = 0.f;
  for (int r = start + rp; r < end; r += 2) {
    float v = h[(long long)r * 128 + col] * sc + sh;
    s += fmaxf(v, 0.f);
  }
  __shared__ float red[256];
  red[tid] = s;
  __syncthreads();
  if (tid < 128) {
    float cnt = fmaxf((float)(end - start), 1.0f);
    pooled[g * 128 + col] = (red[tid] + red[tid + 128]) / cnt;
  }
}

__global__ __launch_bounds__(256) void k_head(const float* __restrict__ pooled,
                                              const float* __restrict__ W,
                                              const float* __restrict__ b,
                                              float* __restrict__ outpre) {
  int idx = blockIdx.x * blockDim.x + threadIdx.x;
  if (idx >= G * NCLS) return;
  int g = idx >> 5, c = idx & 31;
  float acc = b[c];
  const float* pr = pooled + g * 128;
#pragma unroll
  for (int k = 0; k < 128; ++k) acc += pr[k] * W[k * 32 + c];
  outpre[idx] = acc;
}

__global__ __launch_bounds__(1024) void k_bn2(const float* __restrict__ outpre,
                                              const float* __restrict__ w,
                                              const float* __restrict__ b,
                                              float* __restrict__ out) {
  __shared__ float red[1024];
  __shared__ float mus[32], rss[32];
  int tid = threadIdx.x;
  int col = tid & 31, grp = tid >> 5;
  float s = 0.f;
  for (int r = grp; r < G; r += 32) s += outpre[r * 32 + col];
  red[tid] = s;
  __syncthreads();
  for (int off = 512; off >= 32; off >>= 1) {
    if (tid < off) red[tid] += red[tid + off];
    __syncthreads();
  }
  if (tid < 32) mus[col] = red[col] * (1.0f / G);
  __syncthreads();
  float mu = mus[col];
  float s2 = 0.f;
  for (int r = grp; r < G; r += 32) { float d = outpre[r * 32 + col] - mu; s2 += d * d; }
  __syncthreads();
  red[tid] = s2;
  __syncthreads();
  for (int off = 512; off >= 32; off >>= 1) {
    if (tid < off) red[tid] += red[tid + off];
    __syncthreads();
  }
  if (tid < 32) rss[col] = rsqrtf(red[col] * (1.0f / G) + EPS);
  __syncthreads();
  float rs = rss[col], wc = w[col], bc = b[col];
  for (int r = grp; r < G; r += 32)
    out[r * 32 + col] = (outpre[r * 32 + col] - mu) * rs * wc + bc;
}

extern "C" void kernel_launch(void* const* d_in, const int* in_sizes, int n_in,
                              void* d_out, int out_size, void* d_ws, size_t ws_size,
                              hipStream_t stream) {
  const float* x   = (const float*)d_in[0];
  const int* ei    = (const int*)d_in[1];
  const int* batch = (const int*)d_in[2];
  const float* Wg  = (const float*)d_in[3];
  const float* bg  = (const float*)d_in[4];
  const float* w1  = (const float*)d_in[5];
  const float* b1  = (const float*)d_in[6];
  const float* Wo  = (const float*)d_in[7];
  const float* bo  = (const float*)d_in[8];
  const float* w2  = (const float*)d_in[9];
  const float* b2  = (const float*)d_in[10];

  float* ws     = (float*)d_ws;
  float* dinv   = ws;                       // 100352
  float* agg    = ws + 100352;              // N*64
  float* h      = agg + (long long)N * 64;  // N*128
  float* ss     = h + (long long)N * 128;   // 256 (BN1 scale/shift)
  float* sums   = ss + 256;                 // 256 (BN1 atomic accumulators)
  float* pooled = sums + 256;               // G*128
  float* outpre = pooled + G * 128;         // G*32
  int* offsets  = (int*)(outpre + G * 32);  // N+1 (padded to 100416)
  int* srclist  = offsets + 100416;         // E
  int* bucketCursor = srclist + E;          // 64 (padded)
  // bucketBuf aliases h: used only before k_gemm2 writes h (9.63 MB << 51 MB)
  uint2* bucketBuf = (uint2*)h;

  const int* src = ei;
  const int* dst = ei + E;

  hipMemsetAsync(bucketCursor, 0, 64 * sizeof(int), stream);
  hipMemsetAsync(sums, 0, 256 * sizeof(float), stream);
  k_bin<<<BIN_GRID, 256, 0, stream>>>(src, dst, bucketCursor, bucketBuf);
  k_build<<<NBUCK, 1024, 0, stream>>>(bucketCursor, bucketBuf, offsets, dinv, srclist);
  k_gather<<<(N + 15) / 16, 256, 0, stream>>>(offsets, srclist, dinv,
                                              (const float4*)x, (float4*)agg);
  k_gemm2<<<NTILE, 256, 0, stream>>>(agg, Wg, bg, h, sums);
  k_bn1_final<<<1, 128, 0, stream>>>(sums, w1, b1, ss);
  k_pool<<<G, 256, 0, stream>>>(h, ss, batch, pooled);
  k_head<<<(G * NCLS + 255) / 256, 256, 0, stream>>>(pooled, Wo, bo, outpre);
  k_bn2<<<1, 1024, 0, stream>>>(outpre, w2, b2, (float*)d_out);
}

// Round 8
// 244.214 us; speedup vs baseline: 1.4392x; 1.1052x over previous
//
#include <hip/hip_runtime.h>
#include <hip/hip_fp16.h>

constexpr int N    = 100000;
constexpr int E    = 1000000;
constexpr int FIN  = 64;
constexpr int HID  = 128;
constexpr int NCLS = 32;
constexpr int G    = 1024;
constexpr float EPS = 1e-5f;

constexpr int NTILE = (N + 127) / 128;  // 782 row tiles for GEMM

// ---- binned CSR build ----
constexpr int NBUCK = 49;      // dst >> 11
constexpr int NPB   = 2048;    // nodes per bucket
constexpr int EPB   = 2048;    // edges per k_bin block
constexpr int CAP   = 24576;   // bucket capacity
constexpr int BIN_GRID = (E + EPB - 1) / EPB;  // 489

// multi-split edges into buckets by dst>>11; coalesced (src,dst) pair appends
__global__ __launch_bounds__(256) void k_bin(const int* __restrict__ src,
                                             const int* __restrict__ dst,
                                             int* __restrict__ bucketCursor,
                                             uint2* __restrict__ bucketBuf) {
  __shared__ int bcnt[NBUCK];
  __shared__ int bscan[NBUCK];
  __shared__ int bdelta[NBUCK];
  __shared__ int lcur[NBUCK];
  __shared__ uint2 staged[EPB];  // 16 KB
  int tid = threadIdx.x;
  int e0 = blockIdx.x * EPB;
  int cnt = E - e0 < EPB ? E - e0 : EPB;
  for (int i = tid; i < NBUCK; i += 256) bcnt[i] = 0;
  __syncthreads();
  for (int i = tid; i < cnt; i += 256) {
    int d = dst[e0 + i];
    atomicAdd(&bcnt[d >> 11], 1);
  }
  __syncthreads();
  if (tid == 0) {
    int run = 0;
    for (int b = 0; b < NBUCK; ++b) { bscan[b] = run; run += bcnt[b]; }
  }
  __syncthreads();
  if (tid < NBUCK) {
    int base = bcnt[tid] ? atomicAdd(&bucketCursor[tid], bcnt[tid]) : 0;
    bdelta[tid] = base - bscan[tid];
    lcur[tid]   = bscan[tid];
  }
  __syncthreads();
  for (int i = tid; i < cnt; i += 256) {
    int s = src[e0 + i], d = dst[e0 + i];
    int pos = atomicAdd(&lcur[d >> 11], 1);
    staged[pos] = make_uint2((unsigned)s, (unsigned)d);
  }
  __syncthreads();
  for (int i = tid; i < cnt; i += 256) {
    uint2 p = staged[i];
    int b = (int)(p.y >> 11);
    bucketBuf[(long long)b * CAP + bdelta[b] + i] = p;
  }
}

// one block per bucket: LDS count -> offsets+dinv, then LDS-cursor scatter to srclist
__global__ __launch_bounds__(1024) void k_build(const int* __restrict__ bucketLen,
                                                const uint2* __restrict__ bucketBuf,
                                                int* __restrict__ offsets,
                                                float* __restrict__ dinv,
                                                int* __restrict__ srclist) {
  __shared__ int cnt[NPB];
  __shared__ int part[1024];
  __shared__ int bbase;
  int b = blockIdx.x, tid = threadIdx.x;
  int n0 = b << 11;
  int nn = (N - n0 < NPB) ? (N - n0) : NPB;
  int len = bucketLen[b];
  cnt[tid] = 0; cnt[tid + 1024] = 0;
  __syncthreads();
  const uint2* buf = bucketBuf + (long long)b * CAP;
  for (int i = tid; i < len; i += 1024)
    atomicAdd(&cnt[(int)buf[i].y - n0], 1);
  if (tid == 0) {
    int s = 0;
    for (int j = 0; j < b; ++j) s += bucketLen[j];
    bbase = s;
  }
  __syncthreads();
  int c0 = cnt[2 * tid], c1 = cnt[2 * tid + 1];
  int psum = c0 + c1;
  part[tid] = psum;
  __syncthreads();
  for (int off = 1; off < 1024; off <<= 1) {
    int t = (tid >= off) ? part[tid - off] : 0;
    __syncthreads();
    part[tid] += t;
    __syncthreads();
  }
  int excl = part[tid] - psum;
  int base = bbase;
  int o0 = base + excl, o1 = base + excl + c0;
  __syncthreads();
  cnt[2 * tid] = o0; cnt[2 * tid + 1] = o1;
  if (2 * tid < nn) {
    offsets[n0 + 2 * tid] = o0;
    dinv[n0 + 2 * tid] = rsqrtf((float)c0 + 1.0f);
  }
  if (2 * tid + 1 < nn) {
    offsets[n0 + 2 * tid + 1] = o1;
    dinv[n0 + 2 * tid + 1] = rsqrtf((float)c1 + 1.0f);
  }
  if (b == NBUCK - 1 && tid == 1023) offsets[N] = base + part[1023];  // == E
  __syncthreads();
  for (int i = tid; i < len; i += 1024) {
    uint2 p = buf[i];
    int pos = atomicAdd(&cnt[(int)p.y - n0], 1);
    srclist[pos] = (int)p.x;
  }
}

// y16[i] = fp16(x[i] * dinv[i]) — 128 B rows for the gather
__global__ void k_scale(const float4* __restrict__ x4, const float* __restrict__ dinv,
                        float2* __restrict__ y2) {
  int i = blockIdx.x * blockDim.x + threadIdx.x;  // over N*16
  if (i >= N * 16) return;
  int node = i >> 4;
  float c = dinv[node];
  float4 v = x4[i];
  union { float2 f; __half2 h[2]; } u;
  u.h[0] = __float22half2_rn(make_float2(v.x * c, v.y * c));
  u.h[1] = __float22half2_rn(make_float2(v.z * c, v.w * c));
  y2[i] = u.f;
}

// 16 lanes/node, 4-edge unroll: agg[d] = dinv[d]*( y[d] + sum_s y[s] )
__global__ __launch_bounds__(256) void k_gather(const int* __restrict__ offsets,
                                                const int* __restrict__ srclist,
                                                const float* __restrict__ dinv,
                                                const float2* __restrict__ y2,
                                                float4* __restrict__ agg4) {
  int node = blockIdx.x * 16 + (threadIdx.x >> 4);
  int lane = threadIdx.x & 15;
  if (node >= N) return;
  int start = offsets[node], end = offsets[node + 1];
  float cd = dinv[node];

  union { float2 f; __half2 h[2]; } u;
  float4 a0, a1, a2, a3;
  // self term (y[node] already includes dinv[node])
  u.f = y2[node * 16 + lane];
  {
    float2 f01 = __half22float2(u.h[0]);
    float2 f23 = __half22float2(u.h[1]);
    a0 = make_float4(f01.x, f01.y, f23.x, f23.y);
  }
  a1 = make_float4(0.f, 0.f, 0.f, 0.f);
  a2 = a1; a3 = a1;

  int i = start;
  for (; i + 3 < end; i += 4) {
    int s0 = srclist[i], s1 = srclist[i + 1], s2 = srclist[i + 2], s3 = srclist[i + 3];
    union { float2 f; __half2 h[2]; } u0, u1, u2, u3;
    u0.f = y2[(long long)s0 * 16 + lane];
    u1.f = y2[(long long)s1 * 16 + lane];
    u2.f = y2[(long long)s2 * 16 + lane];
    u3.f = y2[(long long)s3 * 16 + lane];
    float2 p, q;
    p = __half22float2(u0.h[0]); q = __half22float2(u0.h[1]);
    a0.x += p.x; a0.y += p.y; a0.z += q.x; a0.w += q.y;
    p = __half22float2(u1.h[0]); q = __half22float2(u1.h[1]);
    a1.x += p.x; a1.y += p.y; a1.z += q.x; a1.w += q.y;
    p = __half22float2(u2.h[0]); q = __half22float2(u2.h[1]);
    a2.x += p.x; a2.y += p.y; a2.z += q.x; a2.w += q.y;
    p = __half22float2(u3.h[0]); q = __half22float2(u3.h[1]);
    a3.x += p.x; a3.y += p.y; a3.z += q.x; a3.w += q.y;
  }
  for (; i < end; ++i) {
    int s = srclist[i];
    u.f = y2[(long long)s * 16 + lane];
    float2 p = __half22float2(u.h[0]);
    float2 q = __half22float2(u.h[1]);
    a0.x += p.x; a0.y += p.y; a0.z += q.x; a0.w += q.y;
  }
  float4 acc;
  acc.x = ((a0.x + a1.x) + (a2.x + a3.x)) * cd;
  acc.y = ((a0.y + a1.y) + (a2.y + a3.y)) * cd;
  acc.z = ((a0.z + a1.z) + (a2.z + a3.z)) * cd;
  acc.w = ((a0.w + a1.w) + (a2.w + a3.w)) * cd;
  agg4[node * 16 + lane] = acc;
}

// h[N,128] = agg[N,64] @ W[64,128] + b, fused BN1 stats via per-block atomics.
__global__ __launch_bounds__(256) void k_gemm2(const float* __restrict__ agg,
                                               const float* __restrict__ W,
                                               const float* __restrict__ b,
                                               float* __restrict__ h,
                                               float* __restrict__ sums) {
  __shared__ float Wl[64 * 128];
  __shared__ float rowT[64 * 128];
  int tid  = threadIdx.x;
  int row0 = blockIdx.x * 128;
  {
    const float4* Wg4 = (const float4*)W;
    float4* Wl4 = (float4*)Wl;
    for (int i = tid; i < 2048; i += 256) Wl4[i] = Wg4[i];
  }
  {
    int r = tid & 127, kh = tid >> 7;
    int grow = row0 + r;
#pragma unroll
    for (int i = 0; i < 8; ++i) {
      int k0 = kh * 32 + i * 4;
      float4 v;
      if (grow < N) v = *(const float4*)&agg[(long long)grow * 64 + k0];
      else          v = make_float4(0.f, 0.f, 0.f, 0.f);
      rowT[(k0 + 0) * 128 + r] = v.x;
      rowT[(k0 + 1) * 128 + r] = v.y;
      rowT[(k0 + 2) * 128 + r] = v.z;
      rowT[(k0 + 3) * 128 + r] = v.w;
    }
  }
  __syncthreads();

  int rt = tid >> 4, ct = tid & 15;
  float acc[8][8];
#pragma unroll
  for (int m = 0; m < 8; ++m)
#pragma unroll
    for (int j = 0; j < 8; ++j) acc[m][j] = 0.f;

#pragma unroll 4
  for (int k = 0; k < 64; ++k) {
    float4 w0 = *(const float4*)&Wl[k * 128 + ct * 8];
    float4 w1 = *(const float4*)&Wl[k * 128 + ct * 8 + 4];
    float4 r0 = *(const float4*)&rowT[k * 128 + rt * 8];
    float4 r1 = *(const float4*)&rowT[k * 128 + rt * 8 + 4];
    float wv[8] = {w0.x, w0.y, w0.z, w0.w, w1.x, w1.y, w1.z, w1.w};
    float rv[8] = {r0.x, r0.y, r0.z, r0.w, r1.x, r1.y, r1.z, r1.w};
#pragma unroll
    for (int m = 0; m < 8; ++m)
#pragma unroll
      for (int j = 0; j < 8; ++j) acc[m][j] += rv[m] * wv[j];
  }

  int cbase = ct * 8;
  float4 b0 = *(const float4*)&b[cbase];
  float4 b1 = *(const float4*)&b[cbase + 4];
  float bias[8] = {b0.x, b0.y, b0.z, b0.w, b1.x, b1.y, b1.z, b1.w};
  float s[8], s2[8];
#pragma unroll
  for (int j = 0; j < 8; ++j) { s[j] = 0.f; s2[j] = 0.f; }
#pragma unroll
  for (int m = 0; m < 8; ++m) {
    int grow = row0 + rt * 8 + m;
    if (grow < N) {
      float hv[8];
#pragma unroll
      for (int j = 0; j < 8; ++j) {
        hv[j] = acc[m][j] + bias[j];
        s[j] += hv[j];
        s2[j] += hv[j] * hv[j];
      }
      float* hp = &h[(long long)grow * 128 + cbase];
      *(float4*)hp       = make_float4(hv[0], hv[1], hv[2], hv[3]);
      *(float4*)(hp + 4) = make_float4(hv[4], hv[5], hv[6], hv[7]);
    }
  }
  __syncthreads();
  float* red = Wl;
#pragma unroll
  for (int j = 0; j < 8; ++j) {
    red[rt * 256 + cbase + j]       = s[j];
    red[rt * 256 + 128 + cbase + j] = s2[j];
  }
  __syncthreads();
  float tot = 0.f;
#pragma unroll 4
  for (int r = 0; r < 16; ++r) tot += red[r * 256 + tid];
  atomicAdd(&sums[tid], tot);
}

__global__ __launch_bounds__(128) void k_bn1_final(const float* __restrict__ sums,
                                                   const float* __restrict__ w,
                                                   const float* __restrict__ bb,
                                                   float* __restrict__ ss) {
  int tid = threadIdx.x;
  float mu  = sums[tid] * (1.0f / N);
  float var = sums[tid + 128] * (1.0f / N) - mu * mu;
  float rs  = rsqrtf(var + EPS);
  float sc  = rs * w[tid];
  ss[tid]       = sc;
  ss[tid + 128] = bb[tid] - mu * sc;
}

__global__ __launch_bounds__(256) void k_pool(const float* __restrict__ h,
                                              const float* __restrict__ ss,
                                              const int* __restrict__ batch,
                                              float* __restrict__ pooled) {
  int g = blockIdx.x;
  int lo = 0, hi = N;
  while (lo < hi) { int m = (lo + hi) >> 1; if (batch[m] < g) lo = m + 1; else hi = m; }
  int lo2 = lo, hi2 = N;
  while (lo2 < hi2) { int m = (lo2 + hi2) >> 1; if (batch[m] < g + 1) lo2 = m + 1; else hi2 = m; }
  int start = lo, end = lo2;
  int tid = threadIdx.x;
  int col = tid & 127, rp = tid >> 7;
  float sc = ss[col], sh = ss[col + 128];
  float s = 0.f;
  for (int r = start + rp; r < end; r += 2) {
    float v = h[(long long)r * 128 + col] * sc + sh;
    s += fmaxf(v, 0.f);
  }
  __shared__ float red[256];
  red[tid] = s;
  __syncthreads();
  if (tid < 128) {
    float cnt = fmaxf((float)(end - start), 1.0f);
    pooled[g * 128 + col] = (red[tid] + red[tid + 128]) / cnt;
  }
}

// head GEMV + per-column partial BN2 stats (LDS reduce + atomics)
__global__ __launch_bounds__(256) void k_head(const float* __restrict__ pooled,
                                              const float* __restrict__ W,
                                              const float* __restrict__ b,
                                              float* __restrict__ outpre,
                                              float* __restrict__ sums2) {
  int idx = blockIdx.x * 256 + threadIdx.x;  // 128 blocks cover G*NCLS exactly
  int g = idx >> 5, c = idx & 31;
  float acc = b[c];
  const float* pr = pooled + g * 128;
#pragma unroll
  for (int k = 0; k < 128; ++k) acc += pr[k] * W[k * 32 + c];
  outpre[idx] = acc;
  __shared__ float red[256], red2[256];
  int tid = threadIdx.x;
  red[tid] = acc; red2[tid] = acc * acc;
  __syncthreads();
  for (int off = 128; off >= 32; off >>= 1) {
    if (tid < off) { red[tid] += red[tid + off]; red2[tid] += red2[tid + off]; }
    __syncthreads();
  }
  if (tid < 32) {
    atomicAdd(&sums2[tid], red[tid]);
    atomicAdd(&sums2[tid + 32], red2[tid]);
  }
}

__global__ void k_bn2f(const float* __restrict__ sums2, const float* __restrict__ w,
                       const float* __restrict__ b, float* __restrict__ ss2) {
  int c = threadIdx.x;  // 32
  float mu  = sums2[c] * (1.0f / G);
  float var = sums2[c + 32] * (1.0f / G) - mu * mu;
  float rs  = rsqrtf(var + EPS);
  float sc  = rs * w[c];
  ss2[c]      = sc;
  ss2[c + 32] = b[c] - mu * sc;
}

__global__ void k_bn2apply(const float* __restrict__ outpre, const float* __restrict__ ss2,
                           float* __restrict__ out) {
  int idx = blockIdx.x * 256 + threadIdx.x;  // 128 blocks
  int c = idx & 31;
  out[idx] = outpre[idx] * ss2[c] + ss2[c + 32];
}

extern "C" void kernel_launch(void* const* d_in, const int* in_sizes, int n_in,
                              void* d_out, int out_size, void* d_ws, size_t ws_size,
                              hipStream_t stream) {
  const float* x   = (const float*)d_in[0];
  const int* ei    = (const int*)d_in[1];
  const int* batch = (const int*)d_in[2];
  const float* Wg  = (const float*)d_in[3];
  const float* bg  = (const float*)d_in[4];
  const float* w1  = (const float*)d_in[5];
  const float* b1  = (const float*)d_in[6];
  const float* Wo  = (const float*)d_in[7];
  const float* bo  = (const float*)d_in[8];
  const float* w2  = (const float*)d_in[9];
  const float* b2  = (const float*)d_in[10];

  float* ws     = (float*)d_ws;
  float* dinv   = ws;                       // 100352
  float* agg    = ws + 100352;              // N*64
  float* h      = agg + (long long)N * 64;  // N*128 (12.8M floats)
  float* ss     = h + (long long)N * 128;   // 256
  float* sums   = ss + 256;                 // 256 (BN1 accum)
  float* sums2  = sums + 256;               // 64  (BN2 accum)  [contiguous w/ sums]
  float* ss2    = sums2 + 64;               // 64
  float* pooled = ss2 + 64;                 // G*128
  float* outpre = pooled + G * 128;         // G*32
  int* offsets  = (int*)(outpre + G * 32);  // 100416
  int* srclist  = offsets + 100416;         // E
  int* bucketCursor = srclist + E;          // 64
  // aliases into h (lifetime-disjoint with h writes in k_gemm2):
  uint2* bucketBuf = (uint2*)h;                       // 9.63 MB at h[0..2.41M)
  float2* y2       = (float2*)(h + 3000000);          // 12.8 MB at h[3.0M..6.2M)

  const int* src = ei;
  const int* dst = ei + E;

  hipMemsetAsync(bucketCursor, 0, 64 * sizeof(int), stream);
  hipMemsetAsync(sums, 0, (256 + 64) * sizeof(float), stream);
  k_bin<<<BIN_GRID, 256, 0, stream>>>(src, dst, bucketCursor, bucketBuf);
  k_build<<<NBUCK, 1024, 0, stream>>>(bucketCursor, bucketBuf, offsets, dinv, srclist);
  k_scale<<<(N * 16 + 255) / 256, 256, 0, stream>>>((const float4*)x, dinv, y2);
  k_gather<<<(N + 15) / 16, 256, 0, stream>>>(offsets, srclist, dinv, y2, (float4*)agg);
  k_gemm2<<<NTILE, 256, 0, stream>>>(agg, Wg, bg, h, sums);
  k_bn1_final<<<1, 128, 0, stream>>>(sums, w1, b1, ss);
  k_pool<<<G, 256, 0, stream>>>(h, ss, batch, pooled);
  k_head<<<128, 256, 0, stream>>>(pooled, Wo, bo, outpre, sums2);
  k_bn2f<<<1, 32, 0, stream>>>(sums2, w2, b2, ss2);
  k_bn2apply<<<128, 256, 0, stream>>>(outpre, ss2, (float*)d_out);
}

// Round 9
// 228.727 us; speedup vs baseline: 1.5366x; 1.0677x over previous
//
#include <hip/hip_runtime.h>
#include <hip/hip_fp16.h>

constexpr int N    = 100000;
constexpr int E    = 1000000;
constexpr int FIN  = 64;
constexpr int HID  = 128;
constexpr int NCLS = 32;
constexpr int G    = 1024;
constexpr float EPS = 1e-5f;

constexpr int NTILE = (N + 127) / 128;  // 782 row tiles for GEMM

// ---- binned CSR build ----
constexpr int NBUCK = 49;
constexpr int NPB   = 2048;
constexpr int EPB   = 2048;
constexpr int CAP   = 24576;
constexpr int BIN_GRID = (E + EPB - 1) / EPB;  // 489

typedef _Float16 half2v __attribute__((ext_vector_type(2)));

__device__ inline float fdot2f(__half2 a, __half2 b, float c) {
#if __has_builtin(__builtin_amdgcn_fdot2)
  return __builtin_amdgcn_fdot2(*(half2v*)&a, *(half2v*)&b, c, false);
#else
  float2 fa = __half22float2(a), fb = __half22float2(b);
  return c + fa.x * fb.x + fa.y * fb.y;
#endif
}

// multi-split edges into buckets by dst>>11; coalesced (src,dst) pair appends
__global__ __launch_bounds__(256) void k_bin(const int* __restrict__ src,
                                             const int* __restrict__ dst,
                                             int* __restrict__ bucketCursor,
                                             uint2* __restrict__ bucketBuf) {
  __shared__ int bcnt[NBUCK];
  __shared__ int bscan[NBUCK];
  __shared__ int bdelta[NBUCK];
  __shared__ int lcur[NBUCK];
  __shared__ uint2 staged[EPB];
  int tid = threadIdx.x;
  int e0 = blockIdx.x * EPB;
  int cnt = E - e0 < EPB ? E - e0 : EPB;
  for (int i = tid; i < NBUCK; i += 256) bcnt[i] = 0;
  __syncthreads();
  for (int i = tid; i < cnt; i += 256) {
    int d = dst[e0 + i];
    atomicAdd(&bcnt[d >> 11], 1);
  }
  __syncthreads();
  if (tid == 0) {
    int run = 0;
    for (int b = 0; b < NBUCK; ++b) { bscan[b] = run; run += bcnt[b]; }
  }
  __syncthreads();
  if (tid < NBUCK) {
    int base = bcnt[tid] ? atomicAdd(&bucketCursor[tid], bcnt[tid]) : 0;
    bdelta[tid] = base - bscan[tid];
    lcur[tid]   = bscan[tid];
  }
  __syncthreads();
  for (int i = tid; i < cnt; i += 256) {
    int s = src[e0 + i], d = dst[e0 + i];
    int pos = atomicAdd(&lcur[d >> 11], 1);
    staged[pos] = make_uint2((unsigned)s, (unsigned)d);
  }
  __syncthreads();
  for (int i = tid; i < cnt; i += 256) {
    uint2 p = staged[i];
    int b = (int)(p.y >> 11);
    bucketBuf[(long long)b * CAP + bdelta[b] + i] = p;
  }
}

// one block per bucket: LDS count -> offsets+dinv, then LDS-cursor scatter to srclist
__global__ __launch_bounds__(1024) void k_build(const int* __restrict__ bucketLen,
                                                const uint2* __restrict__ bucketBuf,
                                                int* __restrict__ offsets,
                                                float* __restrict__ dinv,
                                                int* __restrict__ srclist) {
  __shared__ int cnt[NPB];
  __shared__ int part[1024];
  __shared__ int bbase;
  int b = blockIdx.x, tid = threadIdx.x;
  int n0 = b << 11;
  int nn = (N - n0 < NPB) ? (N - n0) : NPB;
  int len = bucketLen[b];
  cnt[tid] = 0; cnt[tid + 1024] = 0;
  __syncthreads();
  const uint2* buf = bucketBuf + (long long)b * CAP;
  for (int i = tid; i < len; i += 1024)
    atomicAdd(&cnt[(int)buf[i].y - n0], 1);
  if (tid == 0) {
    int s = 0;
    for (int j = 0; j < b; ++j) s += bucketLen[j];
    bbase = s;
  }
  __syncthreads();
  int c0 = cnt[2 * tid], c1 = cnt[2 * tid + 1];
  int psum = c0 + c1;
  part[tid] = psum;
  __syncthreads();
  for (int off = 1; off < 1024; off <<= 1) {
    int t = (tid >= off) ? part[tid - off] : 0;
    __syncthreads();
    part[tid] += t;
    __syncthreads();
  }
  int excl = part[tid] - psum;
  int base = bbase;
  int o0 = base + excl, o1 = base + excl + c0;
  __syncthreads();
  cnt[2 * tid] = o0; cnt[2 * tid + 1] = o1;
  if (2 * tid < nn) {
    offsets[n0 + 2 * tid] = o0;
    dinv[n0 + 2 * tid] = rsqrtf((float)c0 + 1.0f);
  }
  if (2 * tid + 1 < nn) {
    offsets[n0 + 2 * tid + 1] = o1;
    dinv[n0 + 2 * tid + 1] = rsqrtf((float)c1 + 1.0f);
  }
  if (b == NBUCK - 1 && tid == 1023) offsets[N] = base + part[1023];  // == E
  __syncthreads();
  for (int i = tid; i < len; i += 1024) {
    uint2 p = buf[i];
    int pos = atomicAdd(&cnt[(int)p.y - n0], 1);
    srclist[pos] = (int)p.x;
  }
}

// y16[i] = fp16(x[i] * dinv[i]) — 128 B rows for the gather
__global__ void k_scale(const float4* __restrict__ x4, const float* __restrict__ dinv,
                        float2* __restrict__ y2) {
  int i = blockIdx.x * blockDim.x + threadIdx.x;  // over N*16
  if (i >= N * 16) return;
  int node = i >> 4;
  float c = dinv[node];
  float4 v = x4[i];
  union { float2 f; __half2 h[2]; } u;
  u.h[0] = __float22half2_rn(make_float2(v.x * c, v.y * c));
  u.h[1] = __float22half2_rn(make_float2(v.z * c, v.w * c));
  y2[i] = u.f;
}

// W[64][128] f32 -> w2g[kp][col] half2 pairs along k
__global__ void k_wprep(const float* __restrict__ W, __half2* __restrict__ w2g) {
  int idx = blockIdx.x * blockDim.x + threadIdx.x;  // 4096
  if (idx >= 32 * 128) return;
  int kp = idx >> 7, col = idx & 127;
  w2g[idx] = __floats2half2_rn(W[(2 * kp) * 128 + col], W[(2 * kp + 1) * 128 + col]);
}

// 16 lanes/node, 4-edge unroll: agg[d] = fp16( dinv[d]*( y[d] + sum_s y[s] ) )
__global__ __launch_bounds__(256) void k_gather(const int* __restrict__ offsets,
                                                const int* __restrict__ srclist,
                                                const float* __restrict__ dinv,
                                                const float2* __restrict__ y2,
                                                float2* __restrict__ aggh) {
  int node = blockIdx.x * 16 + (threadIdx.x >> 4);
  int lane = threadIdx.x & 15;
  if (node >= N) return;
  int start = offsets[node], end = offsets[node + 1];
  float cd = dinv[node];

  union { float2 f; __half2 h[2]; } u;
  float4 a0, a1, a2, a3;
  u.f = y2[node * 16 + lane];
  {
    float2 f01 = __half22float2(u.h[0]);
    float2 f23 = __half22float2(u.h[1]);
    a0 = make_float4(f01.x, f01.y, f23.x, f23.y);
  }
  a1 = make_float4(0.f, 0.f, 0.f, 0.f);
  a2 = a1; a3 = a1;

  int i = start;
  for (; i + 3 < end; i += 4) {
    int s0 = srclist[i], s1 = srclist[i + 1], s2 = srclist[i + 2], s3 = srclist[i + 3];
    union { float2 f; __half2 h[2]; } u0, u1, u2, u3;
    u0.f = y2[(long long)s0 * 16 + lane];
    u1.f = y2[(long long)s1 * 16 + lane];
    u2.f = y2[(long long)s2 * 16 + lane];
    u3.f = y2[(long long)s3 * 16 + lane];
    float2 p, q;
    p = __half22float2(u0.h[0]); q = __half22float2(u0.h[1]);
    a0.x += p.x; a0.y += p.y; a0.z += q.x; a0.w += q.y;
    p = __half22float2(u1.h[0]); q = __half22float2(u1.h[1]);
    a1.x += p.x; a1.y += p.y; a1.z += q.x; a1.w += q.y;
    p = __half22float2(u2.h[0]); q = __half22float2(u2.h[1]);
    a2.x += p.x; a2.y += p.y; a2.z += q.x; a2.w += q.y;
    p = __half22float2(u3.h[0]); q = __half22float2(u3.h[1]);
    a3.x += p.x; a3.y += p.y; a3.z += q.x; a3.w += q.y;
  }
  for (; i < end; ++i) {
    int s = srclist[i];
    u.f = y2[(long long)s * 16 + lane];
    float2 p = __half22float2(u.h[0]);
    float2 q = __half22float2(u.h[1]);
    a0.x += p.x; a0.y += p.y; a0.z += q.x; a0.w += q.y;
  }
  float4 acc;
  acc.x = ((a0.x + a1.x) + (a2.x + a3.x)) * cd;
  acc.y = ((a0.y + a1.y) + (a2.y + a3.y)) * cd;
  acc.z = ((a0.z + a1.z) + (a2.z + a3.z)) * cd;
  acc.w = ((a0.w + a1.w) + (a2.w + a3.w)) * cd;
  union { float2 f; __half2 h[2]; } o;
  o.h[0] = __floats2half2_rn(acc.x, acc.y);
  o.h[1] = __floats2half2_rn(acc.z, acc.w);
  aggh[node * 16 + lane] = o.f;  // 16 float2 per row = 64 halfs
}

// h2[N,128](fp16) = aggh[N,64](fp16) @ W(fp16 pairs) + b, fused BN1 stats (f32).
// LDS 32 KB total -> ~5 blocks/CU; dot2 inner loop.
__global__ __launch_bounds__(256) void k_gemm2h(const __half2* __restrict__ aggh2,
                                                const __half2* __restrict__ w2g,
                                                const float* __restrict__ b,
                                                __half2* __restrict__ h2,
                                                float* __restrict__ sums) {
  __shared__ __half2 Wl[32 * 128];    // [kp][col] 16 KB
  __shared__ __half2 rowT[32 * 128];  // [kp][row] 16 KB
  int tid  = threadIdx.x;
  int row0 = blockIdx.x * 128;
  {
    const float4* srcv = (const float4*)w2g;
    float4* dstv = (float4*)Wl;
    for (int i = tid; i < 1024; i += 256) dstv[i] = srcv[i];
  }
  {
    int half = tid >> 7;   // 0/1: which 16-kp half of the row
    int r = tid & 127;
    int grow = row0 + r;
#pragma unroll
    for (int c = 0; c < 4; ++c) {
      int kp0 = half * 16 + c * 4;
      float4 v = make_float4(0.f, 0.f, 0.f, 0.f);
      if (grow < N) v = *(const float4*)&aggh2[(long long)grow * 32 + kp0];
      __half2* pv = (__half2*)&v;
      rowT[(kp0 + 0) * 128 + r] = pv[0];
      rowT[(kp0 + 1) * 128 + r] = pv[1];
      rowT[(kp0 + 2) * 128 + r] = pv[2];
      rowT[(kp0 + 3) * 128 + r] = pv[3];
    }
  }
  __syncthreads();

  int rt = tid >> 4, ct = tid & 15;
  float acc[8][8];
#pragma unroll
  for (int m = 0; m < 8; ++m)
#pragma unroll
    for (int j = 0; j < 8; ++j) acc[m][j] = 0.f;

#pragma unroll 2
  for (int kp = 0; kp < 32; ++kp) {
    float4 wv0 = *(const float4*)&Wl[kp * 128 + ct * 8];
    float4 wv1 = *(const float4*)&Wl[kp * 128 + ct * 8 + 4];
    float4 rv0 = *(const float4*)&rowT[kp * 128 + rt * 8];
    float4 rv1 = *(const float4*)&rowT[kp * 128 + rt * 8 + 4];
    __half2 wv[8], rv[8];
    *(float4*)&wv[0] = wv0; *(float4*)&wv[4] = wv1;
    *(float4*)&rv[0] = rv0; *(float4*)&rv[4] = rv1;
#pragma unroll
    for (int m = 0; m < 8; ++m)
#pragma unroll
      for (int j = 0; j < 8; ++j) acc[m][j] = fdot2f(rv[m], wv[j], acc[m][j]);
  }

  int cbase = ct * 8;
  float4 b0 = *(const float4*)&b[cbase];
  float4 b1 = *(const float4*)&b[cbase + 4];
  float bias[8] = {b0.x, b0.y, b0.z, b0.w, b1.x, b1.y, b1.z, b1.w};
  float s[8], s2[8];
#pragma unroll
  for (int j = 0; j < 8; ++j) { s[j] = 0.f; s2[j] = 0.f; }
#pragma unroll
  for (int m = 0; m < 8; ++m) {
    int grow = row0 + rt * 8 + m;
    if (grow < N) {
      float hv[8];
#pragma unroll
      for (int j = 0; j < 8; ++j) {
        hv[j] = acc[m][j] + bias[j];
        s[j] += hv[j];
        s2[j] += hv[j] * hv[j];
      }
      union { float4 f; __half2 h[4]; } o;
      o.h[0] = __floats2half2_rn(hv[0], hv[1]);
      o.h[1] = __floats2half2_rn(hv[2], hv[3]);
      o.h[2] = __floats2half2_rn(hv[4], hv[5]);
      o.h[3] = __floats2half2_rn(hv[6], hv[7]);
      *(float4*)&h2[(long long)grow * 64 + ct * 4] = o.f;
    }
  }
  __syncthreads();
  float* red = (float*)Wl;  // 16*256 floats scratch (16 KB) fits in Wl+rowT
#pragma unroll
  for (int j = 0; j < 8; ++j) {
    red[rt * 256 + cbase + j]       = s[j];
    red[rt * 256 + 128 + cbase + j] = s2[j];
  }
  __syncthreads();
  float tot = 0.f;
#pragma unroll 4
  for (int r = 0; r < 16; ++r) tot += red[r * 256 + tid];
  atomicAdd(&sums[tid], tot);
}

__global__ __launch_bounds__(128) void k_bn1_final(const float* __restrict__ sums,
                                                   const float* __restrict__ w,
                                                   const float* __restrict__ bb,
                                                   float* __restrict__ ss) {
  int tid = threadIdx.x;
  float mu  = sums[tid] * (1.0f / N);
  float var = sums[tid + 128] * (1.0f / N) - mu * mu;
  float rs  = rsqrtf(var + EPS);
  float sc  = rs * w[tid];
  ss[tid]       = sc;
  ss[tid + 128] = bb[tid] - mu * sc;
}

// one block per graph: BN1 + ReLU + mean pool from fp16 h (col-pair per thread)
__global__ __launch_bounds__(256) void k_pool(const __half2* __restrict__ h2,
                                              const float* __restrict__ ss,
                                              const int* __restrict__ batch,
                                              float* __restrict__ pooled) {
  int g = blockIdx.x;
  int lo = 0, hi = N;
  while (lo < hi) { int m = (lo + hi) >> 1; if (batch[m] < g) lo = m + 1; else hi = m; }
  int lo2 = lo, hi2 = N;
  while (lo2 < hi2) { int m = (lo2 + hi2) >> 1; if (batch[m] < g + 1) lo2 = m + 1; else hi2 = m; }
  int start = lo, end = lo2;
  int tid = threadIdx.x;
  int cp = tid & 63, rp = tid >> 6;
  float sc0 = ss[2 * cp], sc1 = ss[2 * cp + 1];
  float sh0 = ss[2 * cp + 128], sh1 = ss[2 * cp + 129];
  float s0 = 0.f, s1 = 0.f;
  for (int r = start + rp; r < end; r += 4) {
    float2 f = __half22float2(h2[(long long)r * 64 + cp]);
    s0 += fmaxf(f.x * sc0 + sh0, 0.f);
    s1 += fmaxf(f.y * sc1 + sh1, 0.f);
  }
  __shared__ float red0[256], red1[256];
  red0[tid] = s0; red1[tid] = s1;
  __syncthreads();
  if (tid < 64) {
#pragma unroll
    for (int q = 1; q < 4; ++q) { s0 += red0[tid + q * 64]; s1 += red1[tid + q * 64]; }
    float cnt = fmaxf((float)(end - start), 1.0f);
    float2 o = make_float2(s0 / cnt, s1 / cnt);
    *(float2*)&pooled[g * 128 + 2 * tid] = o;
  }
}

// head GEMV + per-column partial BN2 stats
__global__ __launch_bounds__(256) void k_head(const float* __restrict__ pooled,
                                              const float* __restrict__ W,
                                              const float* __restrict__ b,
                                              float* __restrict__ outpre,
                                              float* __restrict__ sums2) {
  int idx = blockIdx.x * 256 + threadIdx.x;  // 128 blocks cover G*NCLS exactly
  int g = idx >> 5, c = idx & 31;
  float acc = b[c];
  const float* pr = pooled + g * 128;
#pragma unroll
  for (int k = 0; k < 128; ++k) acc += pr[k] * W[k * 32 + c];
  outpre[idx] = acc;
  __shared__ float red[256], red2[256];
  int tid = threadIdx.x;
  red[tid] = acc; red2[tid] = acc * acc;
  __syncthreads();
  for (int off = 128; off >= 32; off >>= 1) {
    if (tid < off) { red[tid] += red[tid + off]; red2[tid] += red2[tid + off]; }
    __syncthreads();
  }
  if (tid < 32) {
    atomicAdd(&sums2[tid], red[tid]);
    atomicAdd(&sums2[tid + 32], red2[tid]);
  }
}

__global__ void k_bn2f(const float* __restrict__ sums2, const float* __restrict__ w,
                       const float* __restrict__ b, float* __restrict__ ss2) {
  int c = threadIdx.x;  // 32
  float mu  = sums2[c] * (1.0f / G);
  float var = sums2[c + 32] * (1.0f / G) - mu * mu;
  float rs  = rsqrtf(var + EPS);
  float sc  = rs * w[c];
  ss2[c]      = sc;
  ss2[c + 32] = b[c] - mu * sc;
}

__global__ void k_bn2apply(const float* __restrict__ outpre, const float* __restrict__ ss2,
                           float* __restrict__ out) {
  int idx = blockIdx.x * 256 + threadIdx.x;  // 128 blocks
  int c = idx & 31;
  out[idx] = outpre[idx] * ss2[c] + ss2[c + 32];
}

extern "C" void kernel_launch(void* const* d_in, const int* in_sizes, int n_in,
                              void* d_out, int out_size, void* d_ws, size_t ws_size,
                              hipStream_t stream) {
  const float* x   = (const float*)d_in[0];
  const int* ei    = (const int*)d_in[1];
  const int* batch = (const int*)d_in[2];
  const float* Wg  = (const float*)d_in[3];
  const float* bg  = (const float*)d_in[4];
  const float* w1  = (const float*)d_in[5];
  const float* b1  = (const float*)d_in[6];
  const float* Wo  = (const float*)d_in[7];
  const float* bo  = (const float*)d_in[8];
  const float* w2  = (const float*)d_in[9];
  const float* b2  = (const float*)d_in[10];

  float* ws     = (float*)d_ws;
  float* dinv   = ws;                        // 100352 floats
  float* aggh_f = ws + 100352;               // N*64 halfs = 1.6M floats (pad 1600512)
  float* h2_f   = aggh_f + 1600512;          // N*128 halfs = 6.4M floats
  float* ss     = h2_f + 6400000;            // 256
  float* sums   = ss + 256;                  // 256 (BN1 accum)
  float* sums2  = sums + 256;                // 64  (BN2 accum)
  float* ss2    = sums2 + 64;                // 64
  float* pooled = ss2 + 64;                  // G*128
  float* outpre = pooled + G * 128;          // G*32
  int* offsets  = (int*)(outpre + G * 32);   // 100416
  int* srclist  = offsets + 100416;          // E
  int* bucketCursor = srclist + E;           // 64
  __half2* w2g  = (__half2*)(bucketCursor + 64);  // 4096 half2 = 4096 floats
  // aliases into h2 region (dead before k_gemm2h writes h2):
  uint2* bucketBuf = (uint2*)h2_f;                 // 9.63 MB at h2[0..)
  float2* y2       = (float2*)(h2_f + 3100000);    // 12.8 MB, ends at 24.8 MB < 25.6 MB

  const int* src = ei;
  const int* dst = ei + E;

  hipMemsetAsync(bucketCursor, 0, 64 * sizeof(int), stream);
  hipMemsetAsync(sums, 0, (256 + 64) * sizeof(float), stream);
  k_wprep<<<16, 256, 0, stream>>>(Wg, w2g);
  k_bin<<<BIN_GRID, 256, 0, stream>>>(src, dst, bucketCursor, bucketBuf);
  k_build<<<NBUCK, 1024, 0, stream>>>(bucketCursor, bucketBuf, offsets, dinv, srclist);
  k_scale<<<(N * 16 + 255) / 256, 256, 0, stream>>>((const float4*)x, dinv, y2);
  k_gather<<<(N + 15) / 16, 256, 0, stream>>>(offsets, srclist, dinv, y2, (float2*)aggh_f);
  k_gemm2h<<<NTILE, 256, 0, stream>>>((const __half2*)aggh_f, w2g, bg,
                                      (__half2*)h2_f, sums);
  k_bn1_final<<<1, 128, 0, stream>>>(sums, w1, b1, ss);
  k_pool<<<G, 256, 0, stream>>>((const __half2*)h2_f, ss, batch, pooled);
  k_head<<<128, 256, 0, stream>>>(pooled, Wo, bo, outpre, sums2);
  k_bn2f<<<1, 32, 0, stream>>>(sums2, w2, b2, ss2);
  k_bn2apply<<<128, 256, 0, stream>>>(outpre, ss2, (float*)d_out);
}

// Round 11
// 217.871 us; speedup vs baseline: 1.6132x; 1.0498x over previous
//
#include <hip/hip_runtime.h>
#include <hip/hip_fp16.h>

constexpr int N    = 100000;
constexpr int E    = 1000000;
constexpr int FIN  = 64;
constexpr int HID  = 128;
constexpr int NCLS = 32;
constexpr int G    = 1024;
constexpr float EPS = 1e-5f;

constexpr int NTILE = (N + 127) / 128;  // 782 row tiles for GEMM

// ---- binned CSR build ----
constexpr int NBUCK = 98;      // dst >> 10, nodes/bucket = 1024
constexpr int NPB   = 1024;
constexpr int EPB   = 4096;    // edges per k_bin block
constexpr int CAP   = 12288;   // bucket capacity (mean 10204, sigma ~100)
constexpr int BIN_GRID = (E + EPB - 1) / EPB;  // 245

typedef _Float16 half2v __attribute__((ext_vector_type(2)));

__device__ inline float fdot2f(__half2 a, __half2 b, float c) {
#if __has_builtin(__builtin_amdgcn_fdot2)
  return __builtin_amdgcn_fdot2(*(half2v*)&a, *(half2v*)&b, c, false);
#else
  float2 fa = __half22float2(a), fb = __half22float2(b);
  return c + fa.x * fb.x + fa.y * fb.y;
#endif
}

// multi-split edges into buckets by dst>>10; coalesced (src,dst) pair appends
__global__ __launch_bounds__(256) void k_bin(const int* __restrict__ src,
                                             const int* __restrict__ dst,
                                             int* __restrict__ bucketCursor,
                                             uint2* __restrict__ bucketBuf) {
  __shared__ int bcnt[NBUCK];
  __shared__ int bdelta[NBUCK];
  __shared__ int lcur[NBUCK];
  __shared__ int part[128];
  __shared__ uint2 staged[EPB];  // 32 KB
  int tid = threadIdx.x;
  int e0 = blockIdx.x * EPB;
  int cnt = E - e0 < EPB ? E - e0 : EPB;
  for (int i = tid; i < NBUCK; i += 256) bcnt[i] = 0;
  __syncthreads();
  for (int i = tid; i < cnt; i += 256) {
    int d = dst[e0 + i];
    atomicAdd(&bcnt[d >> 10], 1);
  }
  __syncthreads();
  // parallel exclusive scan of bcnt over 128 lanes
  if (tid < 128) part[tid] = (tid < NBUCK) ? bcnt[tid] : 0;
  __syncthreads();
  for (int off = 1; off < 128; off <<= 1) {
    int t = 0;
    if (tid < 128 && tid >= off) t = part[tid - off];
    __syncthreads();
    if (tid < 128) part[tid] += t;
    __syncthreads();
  }
  if (tid < NBUCK) {
    int excl = part[tid] - bcnt[tid];
    int base = bcnt[tid] ? atomicAdd(&bucketCursor[tid], bcnt[tid]) : 0;
    bdelta[tid] = base - excl;
    lcur[tid]   = excl;
  }
  __syncthreads();
  for (int i = tid; i < cnt; i += 256) {
    int s = src[e0 + i], d = dst[e0 + i];
    int pos = atomicAdd(&lcur[d >> 10], 1);
    staged[pos] = make_uint2((unsigned)s, (unsigned)d);
  }
  __syncthreads();
  for (int i = tid; i < cnt; i += 256) {
    uint2 p = staged[i];
    int b = (int)(p.y >> 10);
    bucketBuf[(long long)b * CAP + bdelta[b] + i] = p;
  }
}

// one block per bucket: LDS count -> offsets+dinv, then LDS-cursor scatter to srclist
__global__ __launch_bounds__(1024) void k_build(const int* __restrict__ bucketLen,
                                                const uint2* __restrict__ bucketBuf,
                                                int* __restrict__ offsets,
                                                float* __restrict__ dinv,
                                                int* __restrict__ srclist) {
  __shared__ int cnt[NPB];
  __shared__ int part[1024];
  __shared__ int sh_bbase;
  int b = blockIdx.x, tid = threadIdx.x;
  int n0 = b << 10;
  int nn = (N - n0 < NPB) ? (N - n0) : NPB;
  int len = bucketLen[b];
  cnt[tid] = 0;
  // parallel prefix of bucketLen[0..b) on 128 lanes (replaces serial chain)
  if (tid < 128) part[tid] = (tid < NBUCK) ? bucketLen[tid] : 0;
  __syncthreads();
  for (int off = 1; off < 128; off <<= 1) {
    int t = 0;
    if (tid < 128 && tid >= off) t = part[tid - off];
    __syncthreads();
    if (tid < 128) part[tid] += t;
    __syncthreads();
  }
  if (tid == b) sh_bbase = part[b] - len;
  __syncthreads();
  const uint2* buf = bucketBuf + (long long)b * CAP;
  for (int i = tid; i < len; i += 1024)
    atomicAdd(&cnt[(int)buf[i].y - n0], 1);
  __syncthreads();
  int v = cnt[tid];
  part[tid] = v;
  __syncthreads();
  for (int off = 1; off < 1024; off <<= 1) {
    int t = (tid >= off) ? part[tid - off] : 0;
    __syncthreads();
    part[tid] += t;
    __syncthreads();
  }
  int base = sh_bbase;
  int o = base + part[tid] - v;
  __syncthreads();
  cnt[tid] = o;  // cursor
  if (tid < nn) {
    offsets[n0 + tid] = o;
    dinv[n0 + tid] = rsqrtf((float)v + 1.0f);
  }
  if (b == NBUCK - 1 && tid == 1023) offsets[N] = base + part[1023];  // == E
  __syncthreads();
  for (int i = tid; i < len; i += 1024) {
    uint2 p = buf[i];
    int pos = atomicAdd(&cnt[(int)p.y - n0], 1);
    srclist[pos] = (int)p.x;
  }
}

// y16[i] = fp16(x[i] * dinv[i]) — 128 B rows for the gather
__global__ void k_scale(const float4* __restrict__ x4, const float* __restrict__ dinv,
                        float2* __restrict__ y2) {
  int i = blockIdx.x * blockDim.x + threadIdx.x;  // over N*16
  if (i >= N * 16) return;
  int node = i >> 4;
  float c = dinv[node];
  float4 v = x4[i];
  union { float2 f; __half2 h[2]; } u;
  u.h[0] = __float22half2_rn(make_float2(v.x * c, v.y * c));
  u.h[1] = __float22half2_rn(make_float2(v.z * c, v.w * c));
  y2[i] = u.f;
}

// W[64][128] f32 -> w2g[kp][col] half2 pairs along k; also zeroes accumulators
__global__ void k_wprep(const float* __restrict__ W, __half2* __restrict__ w2g,
                        int* __restrict__ bucketCursor, float* __restrict__ sums) {
  int idx = blockIdx.x * blockDim.x + threadIdx.x;  // 4096
  if (blockIdx.x == 0 && threadIdx.x < 128) bucketCursor[threadIdx.x] = 0;
  if (blockIdx.x == 1 && threadIdx.x < 64) {
    // sums region: 256 BN1 + 64 BN2 accumulators = 320 floats
    float* p = sums + threadIdx.x;
    p[0] = 0.f; p[64] = 0.f; p[128] = 0.f; p[192] = 0.f; p[256] = 0.f;
  }
  if (idx >= 32 * 128) return;
  int kp = idx >> 7, col = idx & 127;
  w2g[idx] = __floats2half2_rn(W[(2 * kp) * 128 + col], W[(2 * kp + 1) * 128 + col]);
}

// 16 lanes/node, 4-edge unroll: agg[d] = fp16( dinv[d]*( y[d] + sum_s y[s] ) )
__global__ __launch_bounds__(256) void k_gather(const int* __restrict__ offsets,
                                                const int* __restrict__ srclist,
                                                const float* __restrict__ dinv,
                                                const float2* __restrict__ y2,
                                                float2* __restrict__ aggh) {
  int node = blockIdx.x * 16 + (threadIdx.x >> 4);
  int lane = threadIdx.x & 15;
  if (node >= N) return;
  int start = offsets[node], end = offsets[node + 1];
  float cd = dinv[node];

  union { float2 f; __half2 h[2]; } u;
  float4 a0, a1, a2, a3;
  u.f = y2[node * 16 + lane];
  {
    float2 f01 = __half22float2(u.h[0]);
    float2 f23 = __half22float2(u.h[1]);
    a0 = make_float4(f01.x, f01.y, f23.x, f23.y);
  }
  a1 = make_float4(0.f, 0.f, 0.f, 0.f);
  a2 = a1; a3 = a1;

  int i = start;
  for (; i + 3 < end; i += 4) {
    int s0 = srclist[i], s1 = srclist[i + 1], s2 = srclist[i + 2], s3 = srclist[i + 3];
    union { float2 f; __half2 h[2]; } u0, u1, u2, u3;
    u0.f = y2[(long long)s0 * 16 + lane];
    u1.f = y2[(long long)s1 * 16 + lane];
    u2.f = y2[(long long)s2 * 16 + lane];
    u3.f = y2[(long long)s3 * 16 + lane];
    float2 p, q;
    p = __half22float2(u0.h[0]); q = __half22float2(u0.h[1]);
    a0.x += p.x; a0.y += p.y; a0.z += q.x; a0.w += q.y;
    p = __half22float2(u1.h[0]); q = __half22float2(u1.h[1]);
    a1.x += p.x; a1.y += p.y; a1.z += q.x; a1.w += q.y;
    p = __half22float2(u2.h[0]); q = __half22float2(u2.h[1]);
    a2.x += p.x; a2.y += p.y; a2.z += q.x; a2.w += q.y;
    p = __half22float2(u3.h[0]); q = __half22float2(u3.h[1]);
    a3.x += p.x; a3.y += p.y; a3.z += q.x; a3.w += q.y;
  }
  for (; i < end; ++i) {
    int s = srclist[i];
    u.f = y2[(long long)s * 16 + lane];
    float2 p = __half22float2(u.h[0]);
    float2 q = __half22float2(u.h[1]);
    a0.x += p.x; a0.y += p.y; a0.z += q.x; a0.w += q.y;
  }
  float4 acc;
  acc.x = ((a0.x + a1.x) + (a2.x + a3.x)) * cd;
  acc.y = ((a0.y + a1.y) + (a2.y + a3.y)) * cd;
  acc.z = ((a0.z + a1.z) + (a2.z + a3.z)) * cd;
  acc.w = ((a0.w + a1.w) + (a2.w + a3.w)) * cd;
  union { float2 f; __half2 h[2]; } o;
  o.h[0] = __floats2half2_rn(acc.x, acc.y);
  o.h[1] = __floats2half2_rn(acc.z, acc.w);
  aggh[node * 16 + lane] = o.f;
}

// h2[N,128](fp16) = aggh[N,64](fp16) @ W(fp16 pairs) + b, fused BN1 stats (f32).
__global__ __launch_bounds__(256) void k_gemm2h(const __half2* __restrict__ aggh2,
                                                const __half2* __restrict__ w2g,
                                                const float* __restrict__ b,
                                                __half2* __restrict__ h2,
                                                float* __restrict__ sums) {
  __shared__ __half2 Wl[32 * 128];    // 16 KB
  __shared__ __half2 rowT[32 * 128];  // 16 KB
  int tid  = threadIdx.x;
  int row0 = blockIdx.x * 128;
  {
    const float4* srcv = (const float4*)w2g;
    float4* dstv = (float4*)Wl;
    for (int i = tid; i < 1024; i += 256) dstv[i] = srcv[i];
  }
  {
    int half = tid >> 7;
    int r = tid & 127;
    int grow = row0 + r;
#pragma unroll
    for (int c = 0; c < 4; ++c) {
      int kp0 = half * 16 + c * 4;
      float4 v = make_float4(0.f, 0.f, 0.f, 0.f);
      if (grow < N) v = *(const float4*)&aggh2[(long long)grow * 32 + kp0];
      __half2* pv = (__half2*)&v;
      rowT[(kp0 + 0) * 128 + r] = pv[0];
      rowT[(kp0 + 1) * 128 + r] = pv[1];
      rowT[(kp0 + 2) * 128 + r] = pv[2];
      rowT[(kp0 + 3) * 128 + r] = pv[3];
    }
  }
  __syncthreads();

  int rt = tid >> 4, ct = tid & 15;
  float acc[8][8];
#pragma unroll
  for (int m = 0; m < 8; ++m)
#pragma unroll
    for (int j = 0; j < 8; ++j) acc[m][j] = 0.f;

#pragma unroll 2
  for (int kp = 0; kp < 32; ++kp) {
    float4 wv0 = *(const float4*)&Wl[kp * 128 + ct * 8];
    float4 wv1 = *(const float4*)&Wl[kp * 128 + ct * 8 + 4];
    float4 rv0 = *(const float4*)&rowT[kp * 128 + rt * 8];
    float4 rv1 = *(const float4*)&rowT[kp * 128 + rt * 8 + 4];
    __half2 wv[8], rv[8];
    *(float4*)&wv[0] = wv0; *(float4*)&wv[4] = wv1;
    *(float4*)&rv[0] = rv0; *(float4*)&rv[4] = rv1;
#pragma unroll
    for (int m = 0; m < 8; ++m)
#pragma unroll
      for (int j = 0; j < 8; ++j) acc[m][j] = fdot2f(rv[m], wv[j], acc[m][j]);
  }

  int cbase = ct * 8;
  float4 b0 = *(const float4*)&b[cbase];
  float4 b1 = *(const float4*)&b[cbase + 4];
  float bias[8] = {b0.x, b0.y, b0.z, b0.w, b1.x, b1.y, b1.z, b1.w};
  float s[8], s2[8];
#pragma unroll
  for (int j = 0; j < 8; ++j) { s[j] = 0.f; s2[j] = 0.f; }
#pragma unroll
  for (int m = 0; m < 8; ++m) {
    int grow = row0 + rt * 8 + m;
    if (grow < N) {
      float hv[8];
#pragma unroll
      for (int j = 0; j < 8; ++j) {
        hv[j] = acc[m][j] + bias[j];
        s[j] += hv[j];
        s2[j] += hv[j] * hv[j];
      }
      union { float4 f; __half2 h[4]; } o;
      o.h[0] = __floats2half2_rn(hv[0], hv[1]);
      o.h[1] = __floats2half2_rn(hv[2], hv[3]);
      o.h[2] = __floats2half2_rn(hv[4], hv[5]);
      o.h[3] = __floats2half2_rn(hv[6], hv[7]);
      *(float4*)&h2[(long long)grow * 64 + ct * 4] = o.f;
    }
  }
  __syncthreads();
  float* red = (float*)Wl;
#pragma unroll
  for (int j = 0; j < 8; ++j) {
    red[rt * 256 + cbase + j]       = s[j];
    red[rt * 256 + 128 + cbase + j] = s2[j];
  }
  __syncthreads();
  float tot = 0.f;
#pragma unroll 4
  for (int r = 0; r < 16; ++r) tot += red[r * 256 + tid];
  atomicAdd(&sums[tid], tot);
}

__global__ __launch_bounds__(128) void k_bn1_final(const float* __restrict__ sums,
                                                   const float* __restrict__ w,
                                                   const float* __restrict__ bb,
                                                   float* __restrict__ ss) {
  int tid = threadIdx.x;
  float mu  = sums[tid] * (1.0f / N);
  float var = sums[tid + 128] * (1.0f / N) - mu * mu;
  float rs  = rsqrtf(var + EPS);
  float sc  = rs * w[tid];
  ss[tid]       = sc;
  ss[tid + 128] = bb[tid] - mu * sc;
}

// one block per graph: BN1 + ReLU + mean pool from fp16 h (col-pair per thread)
__global__ __launch_bounds__(256) void k_pool(const __half2* __restrict__ h2,
                                              const float* __restrict__ ss,
                                              const int* __restrict__ batch,
                                              float* __restrict__ pooled) {
  int g = blockIdx.x;
  int lo = 0, hi = N;
  while (lo < hi) { int m = (lo + hi) >> 1; if (batch[m] < g) lo = m + 1; else hi = m; }
  int lo2 = lo, hi2 = N;
  while (lo2 < hi2) { int m = (lo2 + hi2) >> 1; if (batch[m] < g + 1) lo2 = m + 1; else hi2 = m; }
  int start = lo, end = lo2;
  int tid = threadIdx.x;
  int cp = tid & 63, rp = tid >> 6;
  float sc0 = ss[2 * cp], sc1 = ss[2 * cp + 1];
  float sh0 = ss[2 * cp + 128], sh1 = ss[2 * cp + 129];
  float s0 = 0.f, s1 = 0.f;
  for (int r = start + rp; r < end; r += 4) {
    float2 f = __half22float2(h2[(long long)r * 64 + cp]);
    s0 += fmaxf(f.x * sc0 + sh0, 0.f);
    s1 += fmaxf(f.y * sc1 + sh1, 0.f);
  }
  __shared__ float red0[256], red1[256];
  red0[tid] = s0; red1[tid] = s1;
  __syncthreads();
  if (tid < 64) {
#pragma unroll
    for (int q = 1; q < 4; ++q) { s0 += red0[tid + q * 64]; s1 += red1[tid + q * 64]; }
    float cnt = fmaxf((float)(end - start), 1.0f);
    float2 o = make_float2(s0 / cnt, s1 / cnt);
    *(float2*)&pooled[g * 128 + 2 * tid] = o;
  }
}

// head GEMV + per-column partial BN2 stats
__global__ __launch_bounds__(256) void k_head(const float* __restrict__ pooled,
                                              const float* __restrict__ W,
                                              const float* __restrict__ b,
                                              float* __restrict__ outpre,
                                              float* __restrict__ sums2) {
  int idx = blockIdx.x * 256 + threadIdx.x;  // 128 blocks cover G*NCLS exactly
  int g = idx >> 5, c = idx & 31;
  float acc = b[c];
  const float* pr = pooled + g * 128;
#pragma unroll
  for (int k = 0; k < 128; ++k) acc += pr[k] * W[k * 32 + c];
  outpre[idx] = acc;
  __shared__ float red[256], red2[256];
  int tid = threadIdx.x;
  red[tid] = acc; red2[tid] = acc * acc;
  __syncthreads();
  for (int off = 128; off >= 32; off >>= 1) {
    if (tid < off) { red[tid] += red[tid + off]; red2[tid] += red2[tid + off]; }
    __syncthreads();
  }
  if (tid < 32) {
    atomicAdd(&sums2[tid], red[tid]);
    atomicAdd(&sums2[tid + 32], red2[tid]);
  }
}

__global__ void k_bn2f(const float* __restrict__ sums2, const float* __restrict__ w,
                       const float* __restrict__ b, float* __restrict__ ss2) {
  int c = threadIdx.x;  // 32
  float mu  = sums2[c] * (1.0f / G);
  float var = sums2[c + 32] * (1.0f / G) - mu * mu;
  float rs  = rsqrtf(var + EPS);
  float sc  = rs * w[c];
  ss2[c]      = sc;
  ss2[c + 32] = b[c] - mu * sc;
}

__global__ void k_bn2apply(const float* __restrict__ outpre, const float* __restrict__ ss2,
                           float* __restrict__ out) {
  int idx = blockIdx.x * 256 + threadIdx.x;  // 128 blocks
  int c = idx & 31;
  out[idx] = outpre[idx] * ss2[c] + ss2[c + 32];
}

extern "C" void kernel_launch(void* const* d_in, const int* in_sizes, int n_in,
                              void* d_out, int out_size, void* d_ws, size_t ws_size,
                              hipStream_t stream) {
  const float* x   = (const float*)d_in[0];
  const int* ei    = (const int*)d_in[1];
  const int* batch = (const int*)d_in[2];
  const float* Wg  = (const float*)d_in[3];
  const float* bg  = (const float*)d_in[4];
  const float* w1  = (const float*)d_in[5];
  const float* b1  = (const float*)d_in[6];
  const float* Wo  = (const float*)d_in[7];
  const float* bo  = (const float*)d_in[8];
  const float* w2  = (const float*)d_in[9];
  const float* b2  = (const float*)d_in[10];

  float* ws     = (float*)d_ws;
  float* dinv   = ws;                        // 100352 floats
  float* aggh_f = ws + 100352;               // N*64 halfs (pad 1600512 floats)
  float* h2_f   = aggh_f + 1600512;          // N*128 halfs = 6.4M floats
  float* ss     = h2_f + 6400000;            // 256
  float* sums   = ss + 256;                  // 256 (BN1 accum)
  float* sums2  = sums + 256;                // 64  (BN2 accum)
  float* ss2    = sums2 + 64;                // 64
  float* pooled = ss2 + 64;                  // G*128
  float* outpre = pooled + G * 128;          // G*32
  int* offsets  = (int*)(outpre + G * 32);   // 100416
  int* srclist  = offsets + 100416;          // E
  int* bucketCursor = srclist + E;           // 128
  __half2* w2g  = (__half2*)(bucketCursor + 128);  // 4096 half2
  // aliases into h2 region (dead before k_gemm2h writes h2):
  uint2* bucketBuf = (uint2*)h2_f;                 // 98*12288*8 = 9.63 MB
  float2* y2       = (float2*)(h2_f + 3100000);    // 12.8 MB, ends < 25.6 MB

  const int* src = ei;
  const int* dst = ei + E;

  k_wprep<<<16, 256, 0, stream>>>(Wg, w2g, bucketCursor, sums);
  k_bin<<<BIN_GRID, 256, 0, stream>>>(src, dst, bucketCursor, bucketBuf);
  k_build<<<NBUCK, 1024, 0, stream>>>(bucketCursor, bucketBuf, offsets, dinv, srclist);
  k_scale<<<(N * 16 + 255) / 256, 256, 0, stream>>>((const float4*)x, dinv, y2);
  k_gather<<<(N + 15) / 16, 256, 0, stream>>>(offsets, srclist, dinv, y2, (float2*)aggh_f);
  k_gemm2h<<<NTILE, 256, 0, stream>>>((const __half2*)aggh_f, w2g, bg,
                                      (__half2*)h2_f, sums);
  k_bn1_final<<<1, 128, 0, stream>>>(sums, w1, b1, ss);
  k_pool<<<G, 256, 0, stream>>>((const __half2*)h2_f, ss, batch, pooled);
  k_head<<<128, 256, 0, stream>>>(pooled, Wo, bo, outpre, sums2);
  k_bn2f<<<1, 32, 0, stream>>>(sums2, w2, b2, ss2);
  k_bn2apply<<<128, 256, 0, stream>>>(outpre, ss2, (float*)d_out);
}